// Round 9
// baseline (52.886 us; speedup 1.0000x reference)
//
#include <hip/hip_runtime.h>
#include <math.h>

#define N_MAX 8192
#define N_USERS 1024
#define D 64
#define NCH 32           // fallback chunks of 256 negatives
#define CHSZ 256
#define RG_SLOTS 8       // fallback row-group slots (16 rows each)
#define FB_BLOCKS (NCH * RG_SLOTS)   // 256 fallback blocks, lowest ids
#define NE 8             // elements per build thread (N_MAX / N_USERS)

#define ATOMIC_ST(p, v) __hip_atomic_store((p), (v), __ATOMIC_RELAXED, __HIP_MEMORY_SCOPE_AGENT)
#define ATOMIC_LD(p)    __hip_atomic_load((p), __ATOMIC_RELAXED, __HIP_MEMORY_SCOPE_AGENT)

// Persistent device scratch (rewritten deterministically every launch).
__device__ int   g_nfb;               // # fallback rows
__device__ int   g_ntot;              // total negatives
__device__ int   g_nmask;             // # masked rows
__device__ int   g_done;              // completion counter (reset by build)
__device__ int4  g_plan[N_MAX];       // {code 0=unmasked 1=regular 2=fallback, start, end, tid_i}
__device__ int4  g_klist[N_MAX];      // {k, tid_k, bits(1/q_k), 0}
__device__ int   g_fb[N_MAX];         // fallback row ids
__device__ float g_pos[N_MAX];        // pos_sim for fallback rows      [IC-coherent]
__device__ float g_ps[N_MAX][NCH];    // fallback partial sums          [IC-coherent]
__device__ int   g_pn[N_MAX][NCH];    // fallback partial counts        [IC-coherent]
__device__ float g_row[N_MAX];        // per-row loss (0 if unmasked/fb)[IC-coherent]

__device__ __forceinline__ bool mask_at(const void* m, int k, bool as_int) {
    return as_int ? (((const int*)m)[k] != 0)
                  : (((const unsigned char*)m)[k] != 0);
}

// ---------------------------------------------------------------------------
// Kernel 1: one 1024-thread block. Register-cached single-read pass, LDS
// histogram, shfl scan, merged scatter (klist + plan + fb list + nmask).
// ---------------------------------------------------------------------------
__global__ __launch_bounds__(1024) void build_buckets(
    const float* __restrict__ q,   const int* __restrict__ tids,
    const int* __restrict__ uid,   const void* __restrict__ maskp, int N)
{
    const int t    = threadIdx.x;
    const int lane = t & 63;
    const int w    = t >> 6;
    __shared__ int cntA[N_USERS];
    __shared__ int offs[N_USERS + 1];
    __shared__ int cur[N_USERS];
    __shared__ int wsum[16];
    __shared__ int s_or, s_nfb, s_nmask;

    if (t == 0) { s_or = 0; s_nfb = 0; s_nmask = 0; g_done = 0; }
    cntA[t] = 0;
    __syncthreads();

    // mask dtype probe: int32 0/1 has zero bytes wherever k%4!=0.
    if (t < N && (t & 3))
        if (((const unsigned char*)maskp)[t]) atomicOr(&s_or, 1);
    __syncthreads();
    const bool as_int = (s_or == 0);

    // cache this thread's elements (independent, issued together)
    bool  mv[NE]; int uv[NE], tv[NE]; float qv[NE];
    #pragma unroll
    for (int e = 0; e < NE; ++e) {
        const int idx = t + e * N_USERS;
        if (idx < N) {
            mv[e] = mask_at(maskp, idx, as_int);
            uv[e] = uid[idx];
            tv[e] = tids[idx];
            qv[e] = q[idx];
        } else { mv[e] = true; uv[e] = 0; tv[e] = 0; qv[e] = 1.0f; }
    }

    #pragma unroll
    for (int e = 0; e < NE; ++e) {
        const int idx = t + e * N_USERS;
        if (idx < N && !mv[e]) atomicAdd(&cntA[uv[e]], 1);
    }
    __syncthreads();

    // exclusive scan over 1024 counts: wave shfl-scan + wave-sum scan
    const int own = cntA[t];
    int inc = own;
    #pragma unroll
    for (int off = 1; off < 64; off <<= 1) {
        int u = __shfl_up(inc, off, 64);
        if (lane >= off) inc += u;
    }
    if (lane == 63) wsum[w] = inc;
    __syncthreads();
    if (w == 0) {
        int s = (lane < 16) ? wsum[lane] : 0;
        #pragma unroll
        for (int off = 1; off < 16; off <<= 1) {
            int u = __shfl_up(s, off, 64);
            if (lane >= off) s += u;
        }
        if (lane < 16) wsum[lane] = s;
    }
    __syncthreads();
    const int base = (w > 0) ? wsum[w - 1] : 0;
    offs[t] = base + inc - own;
    cur[t]  = base + inc - own;
    if (t == N_USERS - 1) offs[N_USERS] = base + inc;
    __syncthreads();

    // merged pass from registers: scatter klist / plan / fallback / nmask
    int myMask = 0;
    #pragma unroll
    for (int e = 0; e < NE; ++e) {
        const int idx = t + e * N_USERS;
        if (idx >= N) break;
        if (mv[e]) {
            ++myMask;
            const int o   = offs[uv[e]];
            const int cnt = cntA[uv[e]];
            int code = 1;
            if (cnt == 0) { int p = atomicAdd(&s_nfb, 1); g_fb[p] = idx; code = 2; }
            g_plan[idx] = make_int4(code, o, o + cnt, tv[e]);
        } else {
            const float rq = 1.0f / qv[e];
            int p = atomicAdd(&cur[uv[e]], 1);
            g_klist[p] = make_int4(idx, tv[e], __float_as_int(rq), 0);
            g_plan[idx] = make_int4(0, 0, 0, tv[e]);
        }
    }
    #pragma unroll
    for (int o = 32; o > 0; o >>= 1) myMask += __shfl_xor(myMask, o, 64);
    if (lane == 0) atomicAdd(&s_nmask, myMask);
    __syncthreads();
    if (t == 0) { g_nfb = s_nfb; g_ntot = offs[N_USERS]; g_nmask = s_nmask; }
}

// ---------------------------------------------------------------------------
// Kernel 2 (fused row + finalize), 256-thread blocks.
//  blocks [0, FB_BLOCKS): fallback partials (chunk c x row-group rg).
//  blocks [FB_BLOCKS, ...): 4 waves/block, one regular row per wave.
// Cross-block handoff is FENCE-FREE: all cross-block values use relaxed
// agent-scope atomic stores (write-through to the coherent point / IC —
// no buffer_wbl2), each wave drains vmcnt before the block's barrier, then
// one relaxed agent fetch_add elects the last block, which reads everything
// back with relaxed agent-scope atomic loads. Finalizer math is fixed-order
// -> result deterministic regardless of which block finalizes.
// ---------------------------------------------------------------------------
__global__ __launch_bounds__(256) void row_fin(
    const float* __restrict__ inp, const float* __restrict__ tgt,
    const float* __restrict__ q,   float* __restrict__ out, int N)
{
    const int t    = threadIdx.x;
    const int lane = t & 63;
    const int w    = t >> 6;
    const int bid  = blockIdx.x;

    __shared__ __align__(16) float in_fb[16][D];
    __shared__ int   s_tid[16];
    __shared__ float ws_s[4][16];
    __shared__ int   ws_n[4][16];
    __shared__ float sf[256];
    __shared__ int   s_last;

    if (bid >= FB_BLOCKS) {
        // ---------------- regular rows: one wave each ----------------------
        const int i = (bid - FB_BLOCKS) * 4 + w;
        if (i < N) {
            const int sub = lane & 15;       // float4 slot within a row
            const int kg  = lane >> 4;       // 4 k-groups per wave

            // all independent loads up front
            const float  a  = inp[i * D + lane];
            const float  b  = tgt[i * D + lane];
            const float4 a4 = ((const float4*)(inp + i * D))[sub];
            const float  qi = q[i];
            const int4   pl = g_plan[i];

            float p = a * b;
            #pragma unroll
            for (int o = 32; o > 0; o >>= 1) p += __shfl_xor(p, o, 64);

            if (pl.x == 0) {
                if (lane == 0) ATOMIC_ST(&g_row[i], 0.0f);
            } else if (pl.x == 2) {
                if (lane == 0) { ATOMIC_ST(&g_pos[i], p); ATOMIC_ST(&g_row[i], 0.0f); }
            } else {
                float s = 0.0f;
                int   n = 0;
                for (int j = pl.y + kg; j < pl.z; j += 4) {
                    const int4 kk = g_klist[j];            // broadcast in group
                    const float4 t4 = *(const float4*)(tgt + kk.x * D + (sub << 2));
                    float dot = a4.x * t4.x + a4.y * t4.y + a4.z * t4.z + a4.w * t4.w;
                    #pragma unroll
                    for (int o = 8; o > 0; o >>= 1) dot += __shfl_xor(dot, o, 16);
                    if (sub == 0 && kk.y != pl.w) { s += expf(dot) * __int_as_float(kk.z); n++; }
                }
                s += __shfl_xor(s, 16, 64); s += __shfl_xor(s, 32, 64);
                n += __shfl_xor(n, 16, 64); n += __shfl_xor(n, 32, 64);
                if (lane == 0) {
                    const float neg_sum = (1.0f - qi) * s / fmaxf((float)n, 1.0f);
                    ATOMIC_ST(&g_row[i], log1pf(neg_sum * expf(-p)));
                }
            }
        }
    } else {
        // ---------------- fallback partials --------------------------------
        const int c   = bid & (NCH - 1);
        const int rg0 = bid >> 5;
        const int nfb = g_nfb, ntot = g_ntot;

        for (int rg = rg0; rg * 16 < nfb; rg += RG_SLOTS) {
            const int nr = min(16, nfb - rg * 16);
            for (int e = t; e < (nr << 6); e += 256)
                in_fb[e >> 6][e & 63] = inp[g_fb[rg * 16 + (e >> 6)] * D + (e & 63)];
            if (t < nr) s_tid[t] = g_plan[g_fb[rg * 16 + t]].w;
            __syncthreads();

            const int k_idx = c * CHSZ + t;  // one negative per thread
            float dot[16];
            #pragma unroll
            for (int r = 0; r < 16; ++r) dot[r] = 0.0f;
            int kk_tid = 0; float rq = 0.0f;
            const bool act = (k_idx < ntot);
            if (act) {
                const int4 kk = g_klist[k_idx];
                kk_tid = kk.y; rq = __int_as_float(kk.z);
                const float4* trow = (const float4*)(tgt + kk.x * D);
                #pragma unroll
                for (int d4 = 0; d4 < D / 4; ++d4) {
                    const float4 t4 = trow[d4];
                    #pragma unroll
                    for (int r = 0; r < 16; ++r) {
                        const float4 af = ((const float4*)in_fb[r])[d4];
                        dot[r] += af.x * t4.x + af.y * t4.y + af.z * t4.z + af.w * t4.w;
                    }
                }
            }
            #pragma unroll
            for (int r = 0; r < 16; ++r) {
                const bool hit = act && (kk_tid != s_tid[r]);
                float s = hit ? expf(dot[r]) * rq : 0.0f;
                int   n = hit ? 1 : 0;
                #pragma unroll
                for (int o = 32; o > 0; o >>= 1) {
                    s += __shfl_xor(s, o, 64);
                    n += __shfl_xor(n, o, 64);
                }
                if (lane == 0) { ws_s[w][r] = s; ws_n[w][r] = n; }
            }
            __syncthreads();
            if (w == 0 && lane < nr) {
                ATOMIC_ST(&g_ps[rg * 16 + lane][c],
                          ws_s[0][lane] + ws_s[1][lane] + ws_s[2][lane] + ws_s[3][lane]);
                ATOMIC_ST(&g_pn[rg * 16 + lane][c],
                          ws_n[0][lane] + ws_n[1][lane] + ws_n[2][lane] + ws_n[3][lane]);
            }
            __syncthreads();                 // protect LDS reuse next rg
        }
    }

    // ---------------- epilogue: last block finalizes (fence-free) -----------
    asm volatile("s_waitcnt vmcnt(0)" ::: "memory");   // my stores are at IC
    __syncthreads();                                   // all waves of block done
    if (t == 0)
        s_last = (__hip_atomic_fetch_add(&g_done, 1, __ATOMIC_RELAXED,
                                         __HIP_MEMORY_SCOPE_AGENT) == (int)gridDim.x - 1);
    __syncthreads();
    if (!s_last) return;

    // Phase A: fallback-row losses, in-register (fixed order per thread).
    const int nfb = g_nfb;
    float s = 0.0f;
    for (int r = t; r < nfb; r += 256) {
        float S = 0.0f; int Nn = 0;
        #pragma unroll
        for (int c = 0; c < NCH; ++c) {
            S  += ATOMIC_LD(&g_ps[r][c]);
            Nn += ATOMIC_LD(&g_pn[r][c]);
        }
        const int i = g_fb[r];
        const float neg_sum = (1.0f - q[i]) * S / fmaxf((float)Nn, 1.0f);
        s += log1pf(neg_sum * expf(-ATOMIC_LD(&g_pos[i])));
    }
    // Phase B: sum per-row losses (fb slots hold 0).
    for (int j = t; j < N; j += 256) s += ATOMIC_LD(&g_row[j]);

    sf[t] = s;
    __syncthreads();
    for (int off = 128; off > 0; off >>= 1) {
        if (t < off) sf[t] += sf[t + off];
        __syncthreads();
    }
    if (t == 0) out[0] = sf[0] / (float)g_nmask;
}

extern "C" void kernel_launch(void* const* d_in, const int* in_sizes, int n_in,
                              void* d_out, int out_size, void* d_ws, size_t ws_size,
                              hipStream_t stream) {
    const float* inp  = (const float*)d_in[0];
    const float* tgt  = (const float*)d_in[1];
    const float* q    = (const float*)d_in[2];
    const int*   tids = (const int*)d_in[3];
    const int*   uids = (const int*)d_in[4];
    const void*  mask = d_in[5];
    const int N = in_sizes[2];  // q_probas element count

    build_buckets<<<1, 1024, 0, stream>>>(q, tids, uids, mask, N);
    row_fin<<<FB_BLOCKS + (N + 3) / 4, 256, 0, stream>>>(
        inp, tgt, q, (float*)d_out, N);
}

// Round 10
// 34.439 us; speedup vs baseline: 1.5356x; 1.5356x over previous
//
#include <hip/hip_runtime.h>
#include <math.h>

#define N_MAX 8192
#define N_USERS 1024
#define D 64
#define NCH 32           // fallback chunks of 256 negatives
#define CHSZ 256
#define RG_SLOTS 8       // fallback row-group slots (16 rows each)
#define FB_BLOCKS (NCH * RG_SLOTS)   // 256 fallback blocks, lowest ids
#define NE 8             // elements per build thread (N_MAX / N_USERS)

// Persistent device scratch (rewritten deterministically every launch).
__device__ int   g_nfb;               // # fallback rows
__device__ int   g_ntot;              // total negatives
__device__ int   g_nmask;             // # masked rows
__device__ int4  g_plan[N_MAX];       // {code 0=unmasked 1=regular 2=fallback, start, end, tid_i}
__device__ int4  g_klist[N_MAX];      // {k, tid_k, bits(1/q_k), 0}
__device__ int4  g_fbe[N_MAX];        // fallback rows: {row, tid, bits(1-q), 0}
__device__ float g_pos[N_MAX];        // pos_sim for fallback rows
__device__ float g_ps[N_MAX][NCH];    // fallback partial sums (row-contiguous)
__device__ int   g_pn[N_MAX][NCH];    // fallback partial counts
__device__ float g_row[N_MAX];        // per-row loss (0 for unmasked/fb rows)

__device__ __forceinline__ bool mask_at(const void* m, int k, bool as_int) {
    return as_int ? (((const int*)m)[k] != 0)
                  : (((const unsigned char*)m)[k] != 0);
}

// ---------------------------------------------------------------------------
// Kernel 1: one 1024-thread block. Register-cached single-read pass, LDS
// histogram + shfl scan; klist built in TWO phases: LDS scatter of k-index,
// then fully-coalesced global writeout (gathers are independent & L2-hot).
// ---------------------------------------------------------------------------
__global__ __launch_bounds__(1024) void build_buckets(
    const float* __restrict__ q,   const int* __restrict__ tids,
    const int* __restrict__ uid,   const void* __restrict__ maskp, int N)
{
    const int t    = threadIdx.x;
    const int lane = t & 63;
    const int w    = t >> 6;
    __shared__ int s_list[N_MAX];   // bucketed k-indices (32 KB)
    __shared__ int cntA[N_USERS];
    __shared__ int offs[N_USERS + 1];
    __shared__ int cur[N_USERS];
    __shared__ int wsum[16];
    __shared__ int s_or, s_nfb, s_nmask;

    if (t == 0) { s_or = 0; s_nfb = 0; s_nmask = 0; }
    cntA[t] = 0;
    __syncthreads();

    // mask dtype probe: int32 0/1 has zero bytes wherever k%4!=0.
    if (t < N && (t & 3))
        if (((const unsigned char*)maskp)[t]) atomicOr(&s_or, 1);
    __syncthreads();
    const bool as_int = (s_or == 0);

    // cache this thread's elements (independent, issued together)
    bool  mv[NE]; int uv[NE], tv[NE]; float qv[NE];
    #pragma unroll
    for (int e = 0; e < NE; ++e) {
        const int idx = t + e * N_USERS;
        if (idx < N) {
            mv[e] = mask_at(maskp, idx, as_int);
            uv[e] = uid[idx];
            tv[e] = tids[idx];
            qv[e] = q[idx];
        } else { mv[e] = true; uv[e] = 0; tv[e] = 0; qv[e] = 1.0f; }
    }

    #pragma unroll
    for (int e = 0; e < NE; ++e) {
        const int idx = t + e * N_USERS;
        if (idx < N && !mv[e]) atomicAdd(&cntA[uv[e]], 1);
    }
    __syncthreads();

    // exclusive scan over 1024 counts: wave shfl-scan + wave-sum scan
    const int own = cntA[t];
    int inc = own;
    #pragma unroll
    for (int off = 1; off < 64; off <<= 1) {
        int u = __shfl_up(inc, off, 64);
        if (lane >= off) inc += u;
    }
    if (lane == 63) wsum[w] = inc;
    __syncthreads();
    if (w == 0) {
        int s = (lane < 16) ? wsum[lane] : 0;
        #pragma unroll
        for (int off = 1; off < 16; off <<= 1) {
            int u = __shfl_up(s, off, 64);
            if (lane >= off) s += u;
        }
        if (lane < 16) wsum[lane] = s;
    }
    __syncthreads();
    const int base = (w > 0) ? wsum[w - 1] : 0;
    offs[t] = base + inc - own;
    cur[t]  = base + inc - own;
    if (t == N_USERS - 1) offs[N_USERS] = base + inc;
    __syncthreads();

    // phase 1: LDS scatter of k-index; plan + fallback records; nmask
    int myMask = 0;
    #pragma unroll
    for (int e = 0; e < NE; ++e) {
        const int idx = t + e * N_USERS;
        if (idx >= N) break;
        if (mv[e]) {
            ++myMask;
            const int o   = offs[uv[e]];
            const int cnt = cntA[uv[e]];
            int code = 1;
            if (cnt == 0) {
                int p = atomicAdd(&s_nfb, 1);
                g_fbe[p] = make_int4(idx, tv[e], __float_as_int(1.0f - qv[e]), 0);
                code = 2;
            }
            g_plan[idx] = make_int4(code, o, o + cnt, tv[e]);
        } else {
            int p = atomicAdd(&cur[uv[e]], 1);
            s_list[p] = idx;
            g_plan[idx] = make_int4(0, 0, 0, tv[e]);
        }
    }
    #pragma unroll
    for (int o = 32; o > 0; o >>= 1) myMask += __shfl_xor(myMask, o, 64);
    if (lane == 0) atomicAdd(&s_nmask, myMask);
    __syncthreads();

    // phase 2: coalesced klist writeout (independent gathers, L2-hot)
    const int ntot = offs[N_USERS];
    for (int j = t; j < ntot; j += N_USERS) {
        const int k = s_list[j];
        g_klist[j] = make_int4(k, tids[k], __float_as_int(1.0f / q[k]), 0);
    }
    if (t == 0) { g_nfb = s_nfb; g_ntot = ntot; g_nmask = s_nmask; }
}

// ---------------------------------------------------------------------------
// Kernel 2 (fused), 256-thread blocks.
//  blocks [0, FB_BLOCKS): fallback partials. Block = (chunk c of 256 negs,
//    row-group rg of 16 fb rows); thread-per-negative, ONE gather chain deep,
//    16 dots from LDS-broadcast rows -> shfl reduce -> g_ps/g_pn.
//  blocks [FB_BLOCKS, ...): 4 waves/block, one row per wave. Load list per
//    wave: {a4, t4p, qi, plan}; chain is plan -> klist -> tgt[k] only.
// ---------------------------------------------------------------------------
__global__ __launch_bounds__(256) void row_kernel(
    const float* __restrict__ inp, const float* __restrict__ tgt,
    const float* __restrict__ q,   int N)
{
    const int t    = threadIdx.x;
    const int lane = t & 63;
    const int w    = t >> 6;
    const int bid  = blockIdx.x;

    if (bid >= FB_BLOCKS) {
        // ---------------- regular rows: one wave each ----------------------
        const int i = (bid - FB_BLOCKS) * 4 + w;
        if (i >= N) return;
        const int sub = lane & 15;           // float4 slot within a row
        const int kg  = lane >> 4;           // 4 k-groups per wave

        // all independent loads up front
        const float4 a4  = ((const float4*)(inp + i * D))[sub];
        const float4 t4p = ((const float4*)(tgt + i * D))[sub];
        const float  qi  = q[i];
        const int4   pl  = g_plan[i];

        // pos_sim via 16-lane butterfly (each kg group computes the same)
        float p = a4.x * t4p.x + a4.y * t4p.y + a4.z * t4p.z + a4.w * t4p.w;
        #pragma unroll
        for (int o = 8; o > 0; o >>= 1) p += __shfl_xor(p, o, 16);

        if (pl.x == 0) { if (lane == 0) g_row[i] = 0.0f; return; }
        if (pl.x == 2) { if (lane == 0) g_pos[i] = p;    return; }

        float s = 0.0f;
        int   n = 0;
        for (int j = pl.y + kg; j < pl.z; j += 4) {
            const int4 kk = g_klist[j];                    // broadcast in group
            const float4 t4 = *(const float4*)(tgt + kk.x * D + (sub << 2));
            float dot = a4.x * t4.x + a4.y * t4.y + a4.z * t4.z + a4.w * t4.w;
            #pragma unroll
            for (int o = 8; o > 0; o >>= 1) dot += __shfl_xor(dot, o, 16);
            if (sub == 0 && kk.y != pl.w) { s += expf(dot) * __int_as_float(kk.z); n++; }
        }
        s += __shfl_xor(s, 16, 64); s += __shfl_xor(s, 32, 64);
        n += __shfl_xor(n, 16, 64); n += __shfl_xor(n, 32, 64);
        if (lane == 0) {
            const float neg_sum = (1.0f - qi) * s / fmaxf((float)n, 1.0f);
            g_row[i] = log1pf(neg_sum * expf(-p));
        }
    } else {
        // ---------------- fallback partials --------------------------------
        const int c   = bid & (NCH - 1);     // neg chunk
        const int rg0 = bid >> 5;            // row-group slot
        const int nfb = g_nfb, ntot = g_ntot;
        __shared__ __align__(16) float in_fb[16][D];
        __shared__ int   s_tid[16];
        __shared__ float ws_s[4][16];
        __shared__ int   ws_n[4][16];

        for (int rg = rg0; rg * 16 < nfb; rg += RG_SLOTS) {
            const int nr = min(16, nfb - rg * 16);
            for (int e = t; e < (nr << 6); e += 256)
                in_fb[e >> 6][e & 63] = inp[g_fbe[rg * 16 + (e >> 6)].x * D + (e & 63)];
            if (t < nr) s_tid[t] = g_fbe[rg * 16 + t].y;
            __syncthreads();

            const int k_idx = c * CHSZ + t;  // one negative per thread
            float dot[16];
            #pragma unroll
            for (int r = 0; r < 16; ++r) dot[r] = 0.0f;
            int kk_tid = 0; float rq = 0.0f;
            const bool act = (k_idx < ntot);
            if (act) {
                const int4 kk = g_klist[k_idx];
                kk_tid = kk.y; rq = __int_as_float(kk.z);
                const float4* trow = (const float4*)(tgt + kk.x * D);
                #pragma unroll
                for (int d4 = 0; d4 < D / 4; ++d4) {
                    const float4 t4 = trow[d4];
                    #pragma unroll
                    for (int r = 0; r < 16; ++r) {
                        const float4 af = ((const float4*)in_fb[r])[d4];
                        dot[r] += af.x * t4.x + af.y * t4.y + af.z * t4.z + af.w * t4.w;
                    }
                }
            }
            #pragma unroll
            for (int r = 0; r < 16; ++r) {
                const bool hit = act && (kk_tid != s_tid[r]);
                float s = hit ? expf(dot[r]) * rq : 0.0f;
                int   n = hit ? 1 : 0;
                #pragma unroll
                for (int o = 32; o > 0; o >>= 1) {
                    s += __shfl_xor(s, o, 64);
                    n += __shfl_xor(n, o, 64);
                }
                if (lane == 0) { ws_s[w][r] = s; ws_n[w][r] = n; }
            }
            __syncthreads();
            if (w == 0 && lane < nr) {
                g_ps[rg * 16 + lane][c] = ws_s[0][lane] + ws_s[1][lane] + ws_s[2][lane] + ws_s[3][lane];
                g_pn[rg * 16 + lane][c] = ws_n[0][lane] + ws_n[1][lane] + ws_n[2][lane] + ws_n[3][lane];
            }
            __syncthreads();                 // protect LDS reuse next rg
        }
    }
}

// ---------------------------------------------------------------------------
// Kernel 3: combine fallback partials (vectorized reads, fixed chunk order),
// then fixed-order global reduction -> scalar loss.
// ---------------------------------------------------------------------------
__global__ __launch_bounds__(512) void finalize(float* __restrict__ out, int N)
{
    __shared__ float sf[512];
    const int t = threadIdx.x;

    const int nfb = g_nfb;
    for (int r = t; r < nfb; r += 512) {
        const float4* ps4 = (const float4*)g_ps[r];
        const int4*   pn4 = (const int4*)g_pn[r];
        float S = 0.0f; int Nn = 0;
        #pragma unroll
        for (int c4 = 0; c4 < NCH / 4; ++c4) {
            const float4 v = ps4[c4];
            const int4   u = pn4[c4];
            S  += v.x + v.y + v.z + v.w;
            Nn += u.x + u.y + u.z + u.w;
        }
        const int4 fe = g_fbe[r];
        const float neg_sum = __int_as_float(fe.z) * S / fmaxf((float)Nn, 1.0f);
        g_row[fe.x] = log1pf(neg_sum * expf(-g_pos[fe.x]));
    }
    __syncthreads();

    float s = 0.0f;
    const float4* r4 = (const float4*)g_row;
    for (int j = t; j < N / 4; j += 512) {
        const float4 v = r4[j];
        s += v.x + v.y + v.z + v.w;
    }
    sf[t] = s;
    __syncthreads();
    for (int off = 256; off > 0; off >>= 1) {
        if (t < off) sf[t] += sf[t + off];
        __syncthreads();
    }
    if (t == 0) out[0] = sf[0] / (float)g_nmask;
}

extern "C" void kernel_launch(void* const* d_in, const int* in_sizes, int n_in,
                              void* d_out, int out_size, void* d_ws, size_t ws_size,
                              hipStream_t stream) {
    const float* inp  = (const float*)d_in[0];
    const float* tgt  = (const float*)d_in[1];
    const float* q    = (const float*)d_in[2];
    const int*   tids = (const int*)d_in[3];
    const int*   uids = (const int*)d_in[4];
    const void*  mask = d_in[5];
    const int N = in_sizes[2];  // q_probas element count

    build_buckets<<<1, 1024, 0, stream>>>(q, tids, uids, mask, N);
    row_kernel<<<FB_BLOCKS + (N + 3) / 4, 256, 0, stream>>>(inp, tgt, q, N);
    finalize<<<1, 512, 0, stream>>>((float*)d_out, N);
}

// Round 11
// 30.913 us; speedup vs baseline: 1.7108x; 1.1141x over previous
//
#include <hip/hip_runtime.h>
#include <math.h>

#define N_MAX 8192
#define N_USERS 1024
#define D 64
#define NCH 32           // fallback chunks of 256 negatives
#define CHSZ 256
#define RG_SLOTS 8       // fallback row-group slots (16 rows each)
#define FB_BLOCKS (NCH * RG_SLOTS)   // 256 fallback blocks, lowest ids
#define NE 8             // elements per build thread (N_MAX / N_USERS)

// Persistent device scratch (rewritten deterministically every launch).
__device__ int   g_nfb;               // # fallback rows
__device__ int   g_ntot;              // total negatives
__device__ int   g_nmask;             // # masked rows
__device__ int4  g_plan[N_MAX];       // {code 0=unmasked 1=regular 2=fallback, start, end, tid_i}
__device__ int4  g_klist[N_MAX];      // {k, tid_k, bits(1/q_k), 0}
__device__ int   g_fb[N_MAX];         // fallback row ids
__device__ float g_pos[N_MAX];        // pos_sim for fallback rows
__device__ float g_ps[N_MAX][NCH];    // fallback partial sums (row-contiguous)
__device__ int   g_pn[N_MAX][NCH];    // fallback partial counts
__device__ float g_row[N_MAX];        // per-row loss (0 for unmasked/fb rows)

__device__ __forceinline__ bool mask_at(const void* m, int k, bool as_int) {
    return as_int ? (((const int*)m)[k] != 0)
                  : (((const unsigned char*)m)[k] != 0);
}

// ---------------------------------------------------------------------------
// Kernel 1: one 1024-thread block. Register-cached single-read pass, LDS
// histogram, shfl scan, merged scatter (klist + plan + fb list + nmask).
// (Exact round-8 version — the two-phase LDS variant regressed.)
// ---------------------------------------------------------------------------
__global__ __launch_bounds__(1024) void build_buckets(
    const float* __restrict__ q,   const int* __restrict__ tids,
    const int* __restrict__ uid,   const void* __restrict__ maskp, int N)
{
    const int t    = threadIdx.x;
    const int lane = t & 63;
    const int w    = t >> 6;
    __shared__ int cntA[N_USERS];
    __shared__ int offs[N_USERS + 1];
    __shared__ int cur[N_USERS];
    __shared__ int wsum[16];
    __shared__ int s_or, s_nfb, s_nmask;

    if (t == 0) { s_or = 0; s_nfb = 0; s_nmask = 0; }
    cntA[t] = 0;
    __syncthreads();

    // mask dtype probe: int32 0/1 has zero bytes wherever k%4!=0.
    if (t < N && (t & 3))
        if (((const unsigned char*)maskp)[t]) atomicOr(&s_or, 1);
    __syncthreads();
    const bool as_int = (s_or == 0);

    // cache this thread's elements (independent, issued together)
    bool  mv[NE]; int uv[NE], tv[NE]; float qv[NE];
    #pragma unroll
    for (int e = 0; e < NE; ++e) {
        const int idx = t + e * N_USERS;
        if (idx < N) {
            mv[e] = mask_at(maskp, idx, as_int);
            uv[e] = uid[idx];
            tv[e] = tids[idx];
            qv[e] = q[idx];
        } else { mv[e] = true; uv[e] = 0; tv[e] = 0; qv[e] = 1.0f; }
    }

    #pragma unroll
    for (int e = 0; e < NE; ++e) {
        const int idx = t + e * N_USERS;
        if (idx < N && !mv[e]) atomicAdd(&cntA[uv[e]], 1);
    }
    __syncthreads();

    // exclusive scan over 1024 counts: wave shfl-scan + wave-sum scan
    const int own = cntA[t];
    int inc = own;
    #pragma unroll
    for (int off = 1; off < 64; off <<= 1) {
        int u = __shfl_up(inc, off, 64);
        if (lane >= off) inc += u;
    }
    if (lane == 63) wsum[w] = inc;
    __syncthreads();
    if (w == 0) {
        int s = (lane < 16) ? wsum[lane] : 0;
        #pragma unroll
        for (int off = 1; off < 16; off <<= 1) {
            int u = __shfl_up(s, off, 64);
            if (lane >= off) s += u;
        }
        if (lane < 16) wsum[lane] = s;
    }
    __syncthreads();
    const int base = (w > 0) ? wsum[w - 1] : 0;
    offs[t] = base + inc - own;
    cur[t]  = base + inc - own;
    if (t == N_USERS - 1) offs[N_USERS] = base + inc;
    __syncthreads();

    // merged pass from registers: scatter klist / plan / fallback / nmask
    int myMask = 0;
    #pragma unroll
    for (int e = 0; e < NE; ++e) {
        const int idx = t + e * N_USERS;
        if (idx >= N) break;
        if (mv[e]) {
            ++myMask;
            const int o   = offs[uv[e]];
            const int cnt = cntA[uv[e]];
            int code = 1;
            if (cnt == 0) { int p = atomicAdd(&s_nfb, 1); g_fb[p] = idx; code = 2; }
            g_plan[idx] = make_int4(code, o, o + cnt, tv[e]);
        } else {
            const float rq = 1.0f / qv[e];
            int p = atomicAdd(&cur[uv[e]], 1);
            g_klist[p] = make_int4(idx, tv[e], __float_as_int(rq), 0);
            g_plan[idx] = make_int4(0, 0, 0, tv[e]);
        }
    }
    #pragma unroll
    for (int o = 32; o > 0; o >>= 1) myMask += __shfl_xor(myMask, o, 64);
    if (lane == 0) atomicAdd(&s_nmask, myMask);
    __syncthreads();
    if (t == 0) { g_nfb = s_nfb; g_ntot = offs[N_USERS]; g_nmask = s_nmask; }
}

// ---------------------------------------------------------------------------
// Kernel 2 (fused), 256-thread blocks.
//  blocks [0, FB_BLOCKS): fallback partials. Block = (chunk c of 256 negs,
//    row-group rg of 16 fb rows); thread-per-negative, ONE gather chain deep,
//    16 dots from LDS-broadcast rows -> shfl reduce -> g_ps/g_pn.
//  blocks [FB_BLOCKS, ...): 4 waves/block, one row per wave. Load list per
//    wave: {a4, t4p, qi, plan}; chain is plan -> klist -> tgt[k] only.
// ---------------------------------------------------------------------------
__global__ __launch_bounds__(256) void row_kernel(
    const float* __restrict__ inp, const float* __restrict__ tgt,
    const float* __restrict__ q,   int N)
{
    const int t    = threadIdx.x;
    const int lane = t & 63;
    const int w    = t >> 6;
    const int bid  = blockIdx.x;

    if (bid >= FB_BLOCKS) {
        // ---------------- regular rows: one wave each ----------------------
        const int i = (bid - FB_BLOCKS) * 4 + w;
        if (i >= N) return;
        const int sub = lane & 15;           // float4 slot within a row
        const int kg  = lane >> 4;           // 4 k-groups per wave

        // all independent loads up front
        const float4 a4  = ((const float4*)(inp + i * D))[sub];
        const float4 t4p = ((const float4*)(tgt + i * D))[sub];
        const float  qi  = q[i];
        const int4   pl  = g_plan[i];

        // pos_sim via 16-lane butterfly (each kg group computes the same)
        float p = a4.x * t4p.x + a4.y * t4p.y + a4.z * t4p.z + a4.w * t4p.w;
        #pragma unroll
        for (int o = 8; o > 0; o >>= 1) p += __shfl_xor(p, o, 16);

        if (pl.x == 0) { if (lane == 0) g_row[i] = 0.0f; return; }
        if (pl.x == 2) { if (lane == 0) g_pos[i] = p;    return; }

        float s = 0.0f;
        int   n = 0;
        for (int j = pl.y + kg; j < pl.z; j += 4) {
            const int4 kk = g_klist[j];                    // broadcast in group
            const float4 t4 = *(const float4*)(tgt + kk.x * D + (sub << 2));
            float dot = a4.x * t4.x + a4.y * t4.y + a4.z * t4.z + a4.w * t4.w;
            #pragma unroll
            for (int o = 8; o > 0; o >>= 1) dot += __shfl_xor(dot, o, 16);
            if (sub == 0 && kk.y != pl.w) { s += expf(dot) * __int_as_float(kk.z); n++; }
        }
        s += __shfl_xor(s, 16, 64); s += __shfl_xor(s, 32, 64);
        n += __shfl_xor(n, 16, 64); n += __shfl_xor(n, 32, 64);
        if (lane == 0) {
            const float neg_sum = (1.0f - qi) * s / fmaxf((float)n, 1.0f);
            g_row[i] = log1pf(neg_sum * expf(-p));
        }
    } else {
        // ---------------- fallback partials --------------------------------
        const int c   = bid & (NCH - 1);     // neg chunk
        const int rg0 = bid >> 5;            // row-group slot
        const int nfb = g_nfb, ntot = g_ntot;
        __shared__ __align__(16) float in_fb[16][D];
        __shared__ int   s_tid[16];
        __shared__ float ws_s[4][16];
        __shared__ int   ws_n[4][16];

        for (int rg = rg0; rg * 16 < nfb; rg += RG_SLOTS) {
            const int nr = min(16, nfb - rg * 16);
            for (int e = t; e < (nr << 6); e += 256)
                in_fb[e >> 6][e & 63] = inp[g_fb[rg * 16 + (e >> 6)] * D + (e & 63)];
            if (t < nr) s_tid[t] = g_plan[g_fb[rg * 16 + t]].w;
            __syncthreads();

            const int k_idx = c * CHSZ + t;  // one negative per thread
            float dot[16];
            #pragma unroll
            for (int r = 0; r < 16; ++r) dot[r] = 0.0f;
            int kk_tid = 0; float rq = 0.0f;
            const bool act = (k_idx < ntot);
            if (act) {
                const int4 kk = g_klist[k_idx];
                kk_tid = kk.y; rq = __int_as_float(kk.z);
                const float4* trow = (const float4*)(tgt + kk.x * D);
                #pragma unroll
                for (int d4 = 0; d4 < D / 4; ++d4) {
                    const float4 t4 = trow[d4];
                    #pragma unroll
                    for (int r = 0; r < 16; ++r) {
                        const float4 af = ((const float4*)in_fb[r])[d4];
                        dot[r] += af.x * t4.x + af.y * t4.y + af.z * t4.z + af.w * t4.w;
                    }
                }
            }
            #pragma unroll
            for (int r = 0; r < 16; ++r) {
                const bool hit = act && (kk_tid != s_tid[r]);
                float s = hit ? expf(dot[r]) * rq : 0.0f;
                int   n = hit ? 1 : 0;
                #pragma unroll
                for (int o = 32; o > 0; o >>= 1) {
                    s += __shfl_xor(s, o, 64);
                    n += __shfl_xor(n, o, 64);
                }
                if (lane == 0) { ws_s[w][r] = s; ws_n[w][r] = n; }
            }
            __syncthreads();
            if (w == 0 && lane < nr) {
                g_ps[rg * 16 + lane][c] = ws_s[0][lane] + ws_s[1][lane] + ws_s[2][lane] + ws_s[3][lane];
                g_pn[rg * 16 + lane][c] = ws_n[0][lane] + ws_n[1][lane] + ws_n[2][lane] + ws_n[3][lane];
            }
            __syncthreads();                 // protect LDS reuse next rg
        }
    }
}

// ---------------------------------------------------------------------------
// Kernel 3: combine fallback partials (vectorized reads, fixed chunk order ->
// deterministic), then fixed-order global reduction -> scalar loss.
// ---------------------------------------------------------------------------
__global__ __launch_bounds__(512) void finalize(
    const float* __restrict__ q, float* __restrict__ out, int N)
{
    __shared__ float sf[512];
    const int t = threadIdx.x;

    const int nfb = g_nfb;
    for (int r = t; r < nfb; r += 512) {
        const float4* ps4 = (const float4*)g_ps[r];
        const int4*   pn4 = (const int4*)g_pn[r];
        float S = 0.0f; int Nn = 0;
        #pragma unroll
        for (int c4 = 0; c4 < NCH / 4; ++c4) {
            const float4 v = ps4[c4];
            const int4   u = pn4[c4];
            S  += v.x + v.y + v.z + v.w;
            Nn += u.x + u.y + u.z + u.w;
        }
        const int i = g_fb[r];
        const float neg_sum = (1.0f - q[i]) * S / fmaxf((float)Nn, 1.0f);
        g_row[i] = log1pf(neg_sum * expf(-g_pos[i]));
    }
    __syncthreads();

    float s = 0.0f;
    const float4* r4 = (const float4*)g_row;
    for (int j = t; j < N / 4; j += 512) {
        const float4 v = r4[j];
        s += v.x + v.y + v.z + v.w;
    }
    sf[t] = s;
    __syncthreads();
    for (int off = 256; off > 0; off >>= 1) {
        if (t < off) sf[t] += sf[t + off];
        __syncthreads();
    }
    if (t == 0) out[0] = sf[0] / (float)g_nmask;
}

extern "C" void kernel_launch(void* const* d_in, const int* in_sizes, int n_in,
                              void* d_out, int out_size, void* d_ws, size_t ws_size,
                              hipStream_t stream) {
    const float* inp  = (const float*)d_in[0];
    const float* tgt  = (const float*)d_in[1];
    const float* q    = (const float*)d_in[2];
    const int*   tids = (const int*)d_in[3];
    const int*   uids = (const int*)d_in[4];
    const void*  mask = d_in[5];
    const int N = in_sizes[2];  // q_probas element count

    build_buckets<<<1, 1024, 0, stream>>>(q, tids, uids, mask, N);
    row_kernel<<<FB_BLOCKS + (N + 3) / 4, 256, 0, stream>>>(inp, tgt, q, N);
    finalize<<<1, 512, 0, stream>>>(q, (float*)d_out, N);
}